// Round 4
// baseline (260.505 us; speedup 1.0000x reference)
//
#include <hip/hip_runtime.h>
#include <stdint.h>

// Problem constants (fixed by reference setup_inputs)
constexpr int B_ = 8, N_ = 2048, M_ = 2048, K_ = 64;
constexpr int QROWS = 512;  // M rows staged in LDS per phase (4 phases)

// Workspace layout (float offsets). Total 188416 floats (~754 KB).
constexpr int WS_ACC = 0;       // [1]        global fp32 accumulator
constexpr int WS_CNT = 8;       // [1]        int done-counter for final reduce
constexpr int WS_MU  = 16;      // [B*9]      per-batch mean of targets
constexpr int WS_S   = 256;     // [B*81]     S = C + C^T (C = pinv(cov))
constexpr int WS_MOM = 1024;    // [B*8*64]   per-block raw-moment partials
constexpr int WS_QB  = 8192;    // [B*N]      qb = 0.5 b^T S b
constexpr int WS_UT  = 24576;   // [B][10][M] transposed planes: d=0..8 -> u_d[m], d=9 -> qa[m]

// ---------------------------------------------------------------------------
// Kernel 1: raw moments per (row-block, batch): Sum(y)[9], Sum(yy^T)[45 tri].
// Grid (8, B), 256 rows/block, 1 row/thread, butterfly + LDS partial.
// ---------------------------------------------------------------------------
__global__ __launch_bounds__(256) void stats_kernel(const float* __restrict__ targets,
                                                    float* __restrict__ ws)
{
    const int blk = blockIdx.x, b = blockIdx.y, tid = threadIdx.x;
    const float* row = targets + ((size_t)b * M_ + blk * 256 + tid) * 9;
    float y[9], s[9], cc[45];
#pragma unroll
    for (int d = 0; d < 9; ++d) { y[d] = row[d]; s[d] = y[d]; }
    int idx = 0;
#pragma unroll
    for (int i = 0; i < 9; ++i)
#pragma unroll
        for (int j = i; j < 9; ++j) { cc[idx] = y[i] * y[j]; ++idx; }
#pragma unroll
    for (int o = 32; o; o >>= 1) {
#pragma unroll
        for (int d = 0; d < 9; ++d) s[d] += __shfl_xor(s[d], o, 64);
#pragma unroll
        for (int i = 0; i < 45; ++i) cc[i] += __shfl_xor(cc[i], o, 64);
    }
    __shared__ float red[4][54];
    const int wave = tid >> 6, lane = tid & 63;
    if (lane == 0) {
#pragma unroll
        for (int d = 0; d < 9; ++d) red[wave][d] = s[d];
#pragma unroll
        for (int i = 0; i < 45; ++i) red[wave][9 + i] = cc[i];
    }
    __syncthreads();
    if (tid < 54)
        ws[WS_MOM + (b * 8 + blk) * 64 + tid] =
            red[0][tid] + red[1][tid] + red[2][tid] + red[3][tid];
}

// ---------------------------------------------------------------------------
// Kernel 2: ALL 8 batches' pinv in one 1024-thread block (128 threads/batch).
// mu, cov from moments; S = C + C^T, C = pinv(cov) = inv(cov^T cov) cov^T,
// fp64 Gauss-Jordan in LDS. Barriers are uniform across batches.
// ---------------------------------------------------------------------------
__global__ __launch_bounds__(1024) void pinv_kernel(float* __restrict__ ws)
{
    __shared__ double As[8][81], G[8][81], Inv[8][81], Cm[8][81], fcol[8][9], smu[8][9];
    __shared__ float smom[8][64];
    const int b = threadIdx.x >> 7, t = threadIdx.x & 127;

    if (t < 54) {
        float v = 0.f;
#pragma unroll
        for (int k = 0; k < 8; ++k) v += ws[WS_MOM + (b * 8 + k) * 64 + t];
        smom[b][t] = v;
    }
    __syncthreads();
    if (t < 9) {
        const double m = (double)smom[b][t] / M_;
        smu[b][t] = m;
        ws[WS_MU + b * 9 + t] = (float)m;
    }
    __syncthreads();
    if (t < 81) {  // cov = Sum(yy^T) - M mu mu^T
        const int i = t / 9, j = t % 9;
        const int ii = i < j ? i : j, jj = i < j ? j : i;
        const int tri = ii * 9 - ii * (ii - 1) / 2 + (jj - ii);
        As[b][t] = (double)smom[b][9 + tri] - (double)M_ * smu[b][i] * smu[b][j];
    }
    __syncthreads();
    if (t < 81) {
        const int i = t / 9, j = t % 9;
        double sv = 0.0;
#pragma unroll
        for (int k = 0; k < 9; ++k) sv += As[b][k * 9 + i] * As[b][k * 9 + j];  // A^T A
        G[b][t] = sv;
        Inv[b][t] = (i == j) ? 1.0 : 0.0;
    }
    __syncthreads();

    for (int col = 0; col < 9; ++col) {
        const double p = G[b][col * 9 + col];  // all read before any write
        __syncthreads();
        if (t < 9) {
            G[b][col * 9 + t] /= p;
            Inv[b][col * 9 + t] /= p;
        }
        __syncthreads();
        if (t < 9 && t != col) fcol[b][t] = G[b][t * 9 + col];
        __syncthreads();
        if (t < 81) {
            const int r = t / 9, j = t % 9;
            if (r != col) {
                const double f = fcol[b][r];
                G[b][t]   -= f * G[b][col * 9 + j];
                Inv[b][t] -= f * Inv[b][col * 9 + j];
            }
        }
        __syncthreads();
    }

    if (t < 81) {  // C = inv(A^T A) A^T
        const int i = t / 9, j = t % 9;
        double sv = 0.0;
#pragma unroll
        for (int k = 0; k < 9; ++k) sv += Inv[b][i * 9 + k] * As[b][j * 9 + k];
        Cm[b][t] = sv;
    }
    __syncthreads();
    if (t < 81) {
        const int i = t / 9, j = t % 9;
        ws[WS_S + b * 81 + t] = (float)(Cm[b][i * 9 + j] + Cm[b][j * 9 + i]);  // S = C+C^T
    }
}

// ---------------------------------------------------------------------------
// Kernel 3: transposed-plane U (u_d[m], qa[m]) and QB; zero ACC/CNT.
// ---------------------------------------------------------------------------
__global__ __launch_bounds__(256) void prep_kernel(const float* __restrict__ outputs,
                                                   const float* __restrict__ targets,
                                                   float* __restrict__ ws)
{
    const int gid = blockIdx.x * 256 + threadIdx.x;
    if (gid == 0) {  // ws is re-poisoned before every call
        ws[WS_ACC] = 0.f;
        ((int*)ws)[WS_CNT] = 0;
    }

    if (gid < B_ * M_) {
        const int b = gid >> 11, m = gid & 2047;
        const float* S  = ws + WS_S + b * 81;
        const float* mu = ws + WS_MU + b * 9;
        const float* r  = targets + (size_t)gid * 9;
        float a[9];
#pragma unroll
        for (int d = 0; d < 9; ++d) a[d] = r[d] - mu[d];
        float* P = ws + WS_UT + b * 20480 + m;  // plane stride 2048
        float qa = 0.f;
#pragma unroll
        for (int d = 0; d < 9; ++d) {
            float u = 0.f;
#pragma unroll
            for (int e = 0; e < 9; ++e) u = fmaf(S[d * 9 + e], a[e], u);
            P[d * 2048] = u;
            qa = fmaf(u, a[d], qa);
        }
        P[9 * 2048] = 0.5f * qa;
    } else if (gid < B_ * (M_ + N_)) {
        const int g2 = gid - B_ * M_;
        const int b = g2 >> 11;
        const float* S = ws + WS_S + b * 81;
        const float* r = outputs + (size_t)g2 * 9;
        float bb[9];
#pragma unroll
        for (int d = 0; d < 9; ++d) bb[d] = r[d];
        float q = 0.f;
#pragma unroll
        for (int d = 0; d < 9; ++d) {
            float v = 0.f;
#pragma unroll
            for (int e = 0; e < 9; ++e) v = fmaf(S[d * 9 + e], bb[e], v);
            q = fmaf(v, bb[d], q);
        }
        ws[WS_QB + g2] = 0.5f * q;
    }
}

// ---------------------------------------------------------------------------
// Kernel 4: sum-of-top-64 per column. 2 cols/wave, M in 4 phases of 512 rows
// (20 KB LDS, transposed planes, float2 per lane = 2 rows/read, conflict-free).
// b-vectors in SGPRs (readfirstlane). Exact selection: monotone-uint binary
// search bits 31..12, ballot counting (v_cmp -> SGPR mask, popc on scalar
// pipe), chunked + sched_barrier to cap mask liveness; bit loop NOT unrolled
// (round-3 lesson: full unroll -> giant region -> scratch spills).
// ---------------------------------------------------------------------------
__global__ __launch_bounds__(256) void topk_kernel(const float* __restrict__ outputs,
                                                   float* __restrict__ ws,
                                                   float* __restrict__ out)
{
    __shared__ __align__(16) float sU[QROWS * 10];  // 20480 B: 10 planes x 512
    const int b = blockIdx.y;
    const int tid = threadIdx.x;
    const int wave = tid >> 6, lane = tid & 63;
    const int n0 = blockIdx.x * 8 + wave * 2;  // this wave's two columns

    // Wave-uniform b-vectors -> SGPRs (frees VGPRs, SGPR operand in v_fma).
    const float* brow = outputs + ((size_t)b * N_ + n0) * 9;
    float sba[9], sbb[9];
#pragma unroll
    for (int d = 0; d < 9; ++d) {
        sba[d] = __int_as_float(__builtin_amdgcn_readfirstlane(__float_as_int(brow[d])));
        sbb[d] = __int_as_float(__builtin_amdgcn_readfirstlane(__float_as_int(brow[9 + d])));
    }

    unsigned ua[32], ub[32];
#pragma unroll
    for (int ph = 0; ph < 4; ++ph) {
        __syncthreads();  // protect LDS from previous phase's readers
        const float4* srcB = (const float4*)ws + (WS_UT >> 2) + b * 5120 + ph * 128;
        float4* dst = (float4*)sU;
#pragma unroll
        for (int i = 0; i < 5; ++i) {
            const int t = tid + i * 256, p = t >> 7, r = t & 127;
            dst[t] = srcB[p * 512 + r];
        }
        __syncthreads();

#pragma unroll
        for (int j = 0; j < 4; ++j) {
            const int mi = j * 128 + lane * 2;
            const float2 qa2 = *(const float2*)(sU + 9 * QROWS + mi);
            float a0 = qa2.x, a1 = qa2.y, b0 = qa2.x, b1 = qa2.y;
#pragma unroll
            for (int d = 0; d < 9; ++d) {
                const float2 u2 = *(const float2*)(sU + d * QROWS + mi);
                a0 = fmaf(-u2.x, sba[d], a0);
                a1 = fmaf(-u2.y, sba[d], a1);
                b0 = fmaf(-u2.x, sbb[d], b0);
                b1 = fmaf(-u2.y, sbb[d], b1);
            }
            const unsigned xa0 = __float_as_uint(a0), xa1 = __float_as_uint(a1);
            const unsigned xb0 = __float_as_uint(b0), xb1 = __float_as_uint(b1);
            ua[ph * 8 + j * 2]     = (xa0 & 0x80000000u) ? ~xa0 : (xa0 | 0x80000000u);
            ua[ph * 8 + j * 2 + 1] = (xa1 & 0x80000000u) ? ~xa1 : (xa1 | 0x80000000u);
            ub[ph * 8 + j * 2]     = (xb0 & 0x80000000u) ? ~xb0 : (xb0 | 0x80000000u);
            ub[ph * 8 + j * 2 + 1] = (xb1 & 0x80000000u) ? ~xb1 : (xb1 | 0x80000000u);
        }
    }

    // Binary search for tau (64th largest), bits 31..12 (round-3 verified:
    // absmax 0.0 at this truncation). Ballot counting; chunked so <=8 SGPR
    // mask pairs are ever live.
    unsigned ca = 0u, cb = 0u;
#pragma unroll 1
    for (int bit = 31; bit >= 12; --bit) {
        const unsigned ta = ca | (1u << bit);
        const unsigned tb = cb | (1u << bit);
        int cntA = 0, cntB = 0;
#pragma unroll 1
        for (int c = 0; c < 4; ++c) {
#pragma unroll
            for (int j = c * 8; j < c * 8 + 8; ++j) cntA += __popcll(__ballot(ua[j] >= ta));
#pragma unroll
            for (int j = c * 8; j < c * 8 + 8; ++j) cntB += __popcll(__ballot(ub[j] >= tb));
            __builtin_amdgcn_sched_barrier(0);
        }
        if (cntA >= K_) ca = ta;
        if (cntB >= K_) cb = tb;
    }

    // Exact sum of values strictly above cand + tie adjustment at cand.
    float sa = 0.f, sb = 0.f;
    int ga = 0, gb = 0;
#pragma unroll 1
    for (int c = 0; c < 4; ++c) {
#pragma unroll
        for (int j = c * 8; j < c * 8 + 8; ++j) {
            const unsigned va = ua[j], vb = ub[j];
            const float fa = __uint_as_float((va & 0x80000000u) ? (va ^ 0x80000000u) : ~va);
            const float fb = __uint_as_float((vb & 0x80000000u) ? (vb ^ 0x80000000u) : ~vb);
            const bool pa = va > ca, pb = vb > cb;
            sa += pa ? fa : 0.f;
            sb += pb ? fb : 0.f;
            ga += __popcll(__ballot(pa));
            gb += __popcll(__ballot(pb));
        }
        __builtin_amdgcn_sched_barrier(0);
    }
#pragma unroll
    for (int o = 32; o; o >>= 1) {
        sa += __shfl_xor(sa, o, 64);
        sb += __shfl_xor(sb, o, 64);
    }

    if (lane == 0) {
        const float tva = __uint_as_float((ca & 0x80000000u) ? (ca ^ 0x80000000u) : ~ca);
        const float tvb = __uint_as_float((cb & 0x80000000u) ? (cb ^ 0x80000000u) : ~cb);
        const float qba = ws[WS_QB + b * N_ + n0];
        const float qbb = ws[WS_QB + b * N_ + n0 + 1];
        const float colsum = sa + (float)(K_ - ga) * tva + (float)K_ * qba
                           + sb + (float)(K_ - gb) * tvb + (float)K_ * qbb;
        atomicAdd(ws + WS_ACC, colsum);
    }

    // Last block writes the final mean (divide by B*N*K = 2^20, exact scale).
    __syncthreads();
    if (tid == 0) {
        __threadfence();
        const int done = atomicAdd((int*)ws + WS_CNT, 1);
        if (done == (N_ / 8) * B_ - 1) {
            __threadfence();
            const float acc = atomicAdd(ws + WS_ACC, 0.f);  // device-coherent read
            out[0] = acc * (1.0f / 1048576.0f);
        }
    }
}

// ---------------------------------------------------------------------------
extern "C" void kernel_launch(void* const* d_in, const int* in_sizes, int n_in,
                              void* d_out, int out_size, void* d_ws, size_t ws_size,
                              hipStream_t stream)
{
    (void)in_sizes; (void)n_in; (void)out_size; (void)ws_size;
    const float* outputs = (const float*)d_in[0];  // (B,N,9) fp32
    const float* targets = (const float*)d_in[1];  // (B,M,9) fp32
    float* ws  = (float*)d_ws;
    float* out = (float*)d_out;

    stats_kernel<<<dim3(8, B_), 256, 0, stream>>>(targets, ws);
    pinv_kernel<<<1, 1024, 0, stream>>>(ws);
    prep_kernel<<<(B_ * (M_ + N_)) / 256, 256, 0, stream>>>(outputs, targets, ws);
    topk_kernel<<<dim3(N_ / 8, B_), 256, 0, stream>>>(outputs, ws, out);
}

// Round 5
// 250.146 us; speedup vs baseline: 1.0414x; 1.0414x over previous
//
#include <hip/hip_runtime.h>
#include <stdint.h>

// Problem constants (fixed by reference setup_inputs)
constexpr int B_ = 8, N_ = 2048, M_ = 2048, K_ = 64;
constexpr int QROWS = 512;  // M rows staged in LDS per phase (4 phases)

// Workspace layout (float offsets). Total 188416 floats (~754 KB).
constexpr int WS_ACC = 0;       // [1]        global fp32 accumulator
constexpr int WS_CNT = 8;       // [1]        int done-counter for final reduce
constexpr int WS_MU  = 16;      // [B*9]      per-batch mean of targets
constexpr int WS_S   = 256;     // [B*81]     S = C + C^T (C = pinv(cov))
constexpr int WS_MOM = 1024;    // [B*8*64]   per-block raw-moment partials
constexpr int WS_QB  = 8192;    // [B*N]      qb = 0.5 b^T S b
constexpr int WS_UT  = 24576;   // [B][10][M] transposed planes: d=0..8 -> u_d[m], d=9 -> qa[m]

// ---------------------------------------------------------------------------
// Kernel 1: raw moments per (row-block, batch): Sum(y)[9], Sum(yy^T)[45 tri].
// Grid (8, B), 256 rows/block, 1 row/thread, butterfly + LDS partial.
// ---------------------------------------------------------------------------
__global__ __launch_bounds__(256) void stats_kernel(const float* __restrict__ targets,
                                                    float* __restrict__ ws)
{
    const int blk = blockIdx.x, b = blockIdx.y, tid = threadIdx.x;
    const float* row = targets + ((size_t)b * M_ + blk * 256 + tid) * 9;
    float y[9], s[9], cc[45];
#pragma unroll
    for (int d = 0; d < 9; ++d) { y[d] = row[d]; s[d] = y[d]; }
    int idx = 0;
#pragma unroll
    for (int i = 0; i < 9; ++i)
#pragma unroll
        for (int j = i; j < 9; ++j) { cc[idx] = y[i] * y[j]; ++idx; }
#pragma unroll
    for (int o = 32; o; o >>= 1) {
#pragma unroll
        for (int d = 0; d < 9; ++d) s[d] += __shfl_xor(s[d], o, 64);
#pragma unroll
        for (int i = 0; i < 45; ++i) cc[i] += __shfl_xor(cc[i], o, 64);
    }
    __shared__ float red[4][54];
    const int wave = tid >> 6, lane = tid & 63;
    if (lane == 0) {
#pragma unroll
        for (int d = 0; d < 9; ++d) red[wave][d] = s[d];
#pragma unroll
        for (int i = 0; i < 45; ++i) red[wave][9 + i] = cc[i];
    }
    __syncthreads();
    if (tid < 54)
        ws[WS_MOM + (b * 8 + blk) * 64 + tid] =
            red[0][tid] + red[1][tid] + red[2][tid] + red[3][tid];
}

// ---------------------------------------------------------------------------
// Kernel 2: ALL 8 batches' pinv in one 1024-thread block (128 threads/batch).
// mu, cov from moments; S = C + C^T, C = pinv(cov) = inv(cov^T cov) cov^T,
// fp64 Gauss-Jordan in LDS. Barriers are uniform across batches.
// ---------------------------------------------------------------------------
__global__ __launch_bounds__(1024) void pinv_kernel(float* __restrict__ ws)
{
    __shared__ double As[8][81], G[8][81], Inv[8][81], Cm[8][81], fcol[8][9], smu[8][9];
    __shared__ float smom[8][64];
    const int b = threadIdx.x >> 7, t = threadIdx.x & 127;

    if (t < 54) {
        float v = 0.f;
#pragma unroll
        for (int k = 0; k < 8; ++k) v += ws[WS_MOM + (b * 8 + k) * 64 + t];
        smom[b][t] = v;
    }
    __syncthreads();
    if (t < 9) {
        const double m = (double)smom[b][t] / M_;
        smu[b][t] = m;
        ws[WS_MU + b * 9 + t] = (float)m;
    }
    __syncthreads();
    if (t < 81) {  // cov = Sum(yy^T) - M mu mu^T
        const int i = t / 9, j = t % 9;
        const int ii = i < j ? i : j, jj = i < j ? j : i;
        const int tri = ii * 9 - ii * (ii - 1) / 2 + (jj - ii);
        As[b][t] = (double)smom[b][9 + tri] - (double)M_ * smu[b][i] * smu[b][j];
    }
    __syncthreads();
    if (t < 81) {
        const int i = t / 9, j = t % 9;
        double sv = 0.0;
#pragma unroll
        for (int k = 0; k < 9; ++k) sv += As[b][k * 9 + i] * As[b][k * 9 + j];  // A^T A
        G[b][t] = sv;
        Inv[b][t] = (i == j) ? 1.0 : 0.0;
    }
    __syncthreads();

    for (int col = 0; col < 9; ++col) {
        const double p = G[b][col * 9 + col];  // all read before any write
        __syncthreads();
        if (t < 9) {
            G[b][col * 9 + t] /= p;
            Inv[b][col * 9 + t] /= p;
        }
        __syncthreads();
        if (t < 9 && t != col) fcol[b][t] = G[b][t * 9 + col];
        __syncthreads();
        if (t < 81) {
            const int r = t / 9, j = t % 9;
            if (r != col) {
                const double f = fcol[b][r];
                G[b][t]   -= f * G[b][col * 9 + j];
                Inv[b][t] -= f * Inv[b][col * 9 + j];
            }
        }
        __syncthreads();
    }

    if (t < 81) {  // C = inv(A^T A) A^T
        const int i = t / 9, j = t % 9;
        double sv = 0.0;
#pragma unroll
        for (int k = 0; k < 9; ++k) sv += Inv[b][i * 9 + k] * As[b][j * 9 + k];
        Cm[b][t] = sv;
    }
    __syncthreads();
    if (t < 81) {
        const int i = t / 9, j = t % 9;
        ws[WS_S + b * 81 + t] = (float)(Cm[b][i * 9 + j] + Cm[b][j * 9 + i]);  // S = C+C^T
    }
}

// ---------------------------------------------------------------------------
// Kernel 3: transposed-plane U (u_d[m], qa[m]) and QB; zero ACC/CNT.
// ---------------------------------------------------------------------------
__global__ __launch_bounds__(256) void prep_kernel(const float* __restrict__ outputs,
                                                   const float* __restrict__ targets,
                                                   float* __restrict__ ws)
{
    const int gid = blockIdx.x * 256 + threadIdx.x;
    if (gid == 0) {  // ws is re-poisoned before every call
        ws[WS_ACC] = 0.f;
        ((int*)ws)[WS_CNT] = 0;
    }

    if (gid < B_ * M_) {
        const int b = gid >> 11, m = gid & 2047;
        const float* S  = ws + WS_S + b * 81;
        const float* mu = ws + WS_MU + b * 9;
        const float* r  = targets + (size_t)gid * 9;
        float a[9];
#pragma unroll
        for (int d = 0; d < 9; ++d) a[d] = r[d] - mu[d];
        float* P = ws + WS_UT + b * 20480 + m;  // plane stride 2048
        float qa = 0.f;
#pragma unroll
        for (int d = 0; d < 9; ++d) {
            float u = 0.f;
#pragma unroll
            for (int e = 0; e < 9; ++e) u = fmaf(S[d * 9 + e], a[e], u);
            P[d * 2048] = u;
            qa = fmaf(u, a[d], qa);
        }
        P[9 * 2048] = 0.5f * qa;
    } else if (gid < B_ * (M_ + N_)) {
        const int g2 = gid - B_ * M_;
        const int b = g2 >> 11;
        const float* S = ws + WS_S + b * 81;
        const float* r = outputs + (size_t)g2 * 9;
        float bb[9];
#pragma unroll
        for (int d = 0; d < 9; ++d) bb[d] = r[d];
        float q = 0.f;
#pragma unroll
        for (int d = 0; d < 9; ++d) {
            float v = 0.f;
#pragma unroll
            for (int e = 0; e < 9; ++e) v = fmaf(S[d * 9 + e], bb[e], v);
            q = fmaf(v, bb[d], q);
        }
        ws[WS_QB + g2] = 0.5f * q;
    }
}

// ---------------------------------------------------------------------------
// Kernel 4: sum-of-top-64 per column. 2 cols/wave, M in 4 phases of 512 rows
// (20 KB LDS, transposed planes, float2/lane). b-vectors in SGPRs. Exact
// selection: monotone-uint binary search bits 31..12, ballot counting.
// REGISTER DISCIPLINE (rounds 3+4 lessons):
//  - every ua[]/ub[] index is a compile-time constant (runtime index -> the
//    compiler demotes the arrays to scratch: round 4, VGPR=48, 183 us)
//  - bit loop is #pragma unroll 1 (full unroll -> giant region -> spills:
//    round 3, 22 MB scratch writes)
//  - amdgpu_waves_per_eu(4,4) pins the allocator budget to 512/4 = 128 VGPRs
//    so the occupancy heuristic doesn't squeeze to 64 and spill (round 3).
// Last block folds the final mean into d_out (device-scope counter).
// ---------------------------------------------------------------------------
__global__ __launch_bounds__(256)
__attribute__((amdgpu_waves_per_eu(4, 4)))
void topk_kernel(const float* __restrict__ outputs,
                 float* __restrict__ ws,
                 float* __restrict__ out)
{
    __shared__ __align__(16) float sU[QROWS * 10];  // 20480 B: 10 planes x 512
    const int b = blockIdx.y;
    const int tid = threadIdx.x;
    const int wave = tid >> 6, lane = tid & 63;
    const int n0 = blockIdx.x * 8 + wave * 2;  // this wave's two columns

    // Wave-uniform b-vectors -> SGPRs (frees VGPRs, SGPR operand in v_fma).
    const float* brow = outputs + ((size_t)b * N_ + n0) * 9;
    float sba[9], sbb[9];
#pragma unroll
    for (int d = 0; d < 9; ++d) {
        sba[d] = __int_as_float(__builtin_amdgcn_readfirstlane(__float_as_int(brow[d])));
        sbb[d] = __int_as_float(__builtin_amdgcn_readfirstlane(__float_as_int(brow[9 + d])));
    }

    unsigned ua[32], ub[32];
#pragma unroll
    for (int ph = 0; ph < 4; ++ph) {
        __syncthreads();  // protect LDS from previous phase's readers
        const float4* srcB = (const float4*)ws + (WS_UT >> 2) + b * 5120 + ph * 128;
        float4* dst = (float4*)sU;
#pragma unroll
        for (int i = 0; i < 5; ++i) {
            const int t = tid + i * 256, p = t >> 7, r = t & 127;
            dst[t] = srcB[p * 512 + r];
        }
        __syncthreads();

#pragma unroll
        for (int j = 0; j < 4; ++j) {
            const int mi = j * 128 + lane * 2;
            const float2 qa2 = *(const float2*)(sU + 9 * QROWS + mi);
            float a0 = qa2.x, a1 = qa2.y, b0 = qa2.x, b1 = qa2.y;
#pragma unroll
            for (int d = 0; d < 9; ++d) {
                const float2 u2 = *(const float2*)(sU + d * QROWS + mi);
                a0 = fmaf(-u2.x, sba[d], a0);
                a1 = fmaf(-u2.y, sba[d], a1);
                b0 = fmaf(-u2.x, sbb[d], b0);
                b1 = fmaf(-u2.y, sbb[d], b1);
            }
            const unsigned xa0 = __float_as_uint(a0), xa1 = __float_as_uint(a1);
            const unsigned xb0 = __float_as_uint(b0), xb1 = __float_as_uint(b1);
            ua[ph * 8 + j * 2]     = (xa0 & 0x80000000u) ? ~xa0 : (xa0 | 0x80000000u);
            ua[ph * 8 + j * 2 + 1] = (xa1 & 0x80000000u) ? ~xa1 : (xa1 | 0x80000000u);
            ub[ph * 8 + j * 2]     = (xb0 & 0x80000000u) ? ~xb0 : (xb0 | 0x80000000u);
            ub[ph * 8 + j * 2 + 1] = (xb1 & 0x80000000u) ? ~xb1 : (xb1 | 0x80000000u);
        }
    }

    // Binary search for tau (64th largest), bits 31..12 (rounds 2-4 verified
    // exact at this truncation). v_cmp -> SGPR mask, popcount+sum co-issued
    // on the scalar pipe; thresholds are wave-uniform SGPRs.
    unsigned ca = 0u, cb = 0u;
#pragma unroll 1
    for (int bit = 31; bit >= 12; --bit) {
        const unsigned ta = ca | (1u << bit);
        const unsigned tb = cb | (1u << bit);
        int cntA = 0, cntB = 0;
#pragma unroll
        for (int j = 0; j < 32; ++j) cntA += __popcll(__ballot(ua[j] >= ta));
#pragma unroll
        for (int j = 0; j < 32; ++j) cntB += __popcll(__ballot(ub[j] >= tb));
        if (cntA >= K_) ca = ta;
        if (cntB >= K_) cb = tb;
    }

    // Exact sum of values strictly above cand + tie adjustment at cand.
    float sa = 0.f, sb = 0.f;
    int ga = 0, gb = 0;
#pragma unroll
    for (int j = 0; j < 32; ++j) {
        const unsigned va = ua[j], vb = ub[j];
        const float fa = __uint_as_float((va & 0x80000000u) ? (va ^ 0x80000000u) : ~va);
        const float fb = __uint_as_float((vb & 0x80000000u) ? (vb ^ 0x80000000u) : ~vb);
        const bool pa = va > ca, pb = vb > cb;
        sa += pa ? fa : 0.f;
        sb += pb ? fb : 0.f;
        ga += __popcll(__ballot(pa));
        gb += __popcll(__ballot(pb));
    }
#pragma unroll
    for (int o = 32; o; o >>= 1) {
        sa += __shfl_xor(sa, o, 64);
        sb += __shfl_xor(sb, o, 64);
    }

    if (lane == 0) {
        const float tva = __uint_as_float((ca & 0x80000000u) ? (ca ^ 0x80000000u) : ~ca);
        const float tvb = __uint_as_float((cb & 0x80000000u) ? (cb ^ 0x80000000u) : ~cb);
        const float qba = ws[WS_QB + b * N_ + n0];
        const float qbb = ws[WS_QB + b * N_ + n0 + 1];
        const float colsum = sa + (float)(K_ - ga) * tva + (float)K_ * qba
                           + sb + (float)(K_ - gb) * tvb + (float)K_ * qbb;
        atomicAdd(ws + WS_ACC, colsum);
    }

    // Last block writes the final mean (divide by B*N*K = 2^20, exact scale).
    __syncthreads();
    if (tid == 0) {
        __threadfence();
        const int done = atomicAdd((int*)ws + WS_CNT, 1);
        if (done == (N_ / 8) * B_ - 1) {
            __threadfence();
            const float acc = atomicAdd(ws + WS_ACC, 0.f);  // device-coherent read
            out[0] = acc * (1.0f / 1048576.0f);
        }
    }
}

// ---------------------------------------------------------------------------
extern "C" void kernel_launch(void* const* d_in, const int* in_sizes, int n_in,
                              void* d_out, int out_size, void* d_ws, size_t ws_size,
                              hipStream_t stream)
{
    (void)in_sizes; (void)n_in; (void)out_size; (void)ws_size;
    const float* outputs = (const float*)d_in[0];  // (B,N,9) fp32
    const float* targets = (const float*)d_in[1];  // (B,M,9) fp32
    float* ws  = (float*)d_ws;
    float* out = (float*)d_out;

    stats_kernel<<<dim3(8, B_), 256, 0, stream>>>(targets, ws);
    pinv_kernel<<<1, 1024, 0, stream>>>(ws);
    prep_kernel<<<(B_ * (M_ + N_)) / 256, 256, 0, stream>>>(outputs, targets, ws);
    topk_kernel<<<dim3(N_ / 8, B_), 256, 0, stream>>>(outputs, ws, out);
}

// Round 6
// 218.701 us; speedup vs baseline: 1.1911x; 1.1438x over previous
//
#include <hip/hip_runtime.h>
#include <stdint.h>

// Problem constants (fixed by reference setup_inputs)
constexpr int B_ = 8, N_ = 2048, M_ = 2048, K_ = 64;
constexpr int QROWS = 512;  // M rows staged in LDS per phase (4 phases)

// Workspace layout (float offsets). Total 188416 floats (~754 KB).
constexpr int WS_ACC = 0;       // [1]        global fp32 accumulator
constexpr int WS_CNT = 8;       // [1]        int done-counter for final reduce
constexpr int WS_MU  = 16;      // [B*9]      per-batch mean of targets
constexpr int WS_S   = 256;     // [B*81]     S = C + C^T (C = pinv(cov))
constexpr int WS_MOM = 1024;    // [B*8*64]   per-block raw-moment partials
constexpr int WS_QB  = 8192;    // [B*N]      qb = 0.5 b^T S b
constexpr int WS_UT  = 24576;   // [B][10][M] transposed planes: d=0..8 -> u_d[m], d=9 -> qa[m]

// ---------------------------------------------------------------------------
// Kernel 1: raw moments per (row-block, batch): Sum(y)[9], Sum(yy^T)[45 tri].
// Grid (8, B), 256 rows/block, 1 row/thread, butterfly + LDS partial.
// ---------------------------------------------------------------------------
__global__ __launch_bounds__(256) void stats_kernel(const float* __restrict__ targets,
                                                    float* __restrict__ ws)
{
    const int blk = blockIdx.x, b = blockIdx.y, tid = threadIdx.x;
    const float* row = targets + ((size_t)b * M_ + blk * 256 + tid) * 9;
    float y[9], s[9], cc[45];
#pragma unroll
    for (int d = 0; d < 9; ++d) { y[d] = row[d]; s[d] = y[d]; }
    int idx = 0;
#pragma unroll
    for (int i = 0; i < 9; ++i)
#pragma unroll
        for (int j = i; j < 9; ++j) { cc[idx] = y[i] * y[j]; ++idx; }
#pragma unroll
    for (int o = 32; o; o >>= 1) {
#pragma unroll
        for (int d = 0; d < 9; ++d) s[d] += __shfl_xor(s[d], o, 64);
#pragma unroll
        for (int i = 0; i < 45; ++i) cc[i] += __shfl_xor(cc[i], o, 64);
    }
    __shared__ float red[4][54];
    const int wave = tid >> 6, lane = tid & 63;
    if (lane == 0) {
#pragma unroll
        for (int d = 0; d < 9; ++d) red[wave][d] = s[d];
#pragma unroll
        for (int i = 0; i < 45; ++i) red[wave][9 + i] = cc[i];
    }
    __syncthreads();
    if (tid < 54)
        ws[WS_MOM + (b * 8 + blk) * 64 + tid] =
            red[0][tid] + red[1][tid] + red[2][tid] + red[3][tid];
}

// ---------------------------------------------------------------------------
// Kernel 2: ALL 8 batches' pinv in one 1024-thread block (128 threads/batch).
// mu, cov from moments; S = C + C^T, C = pinv(cov) = inv(cov^T cov) cov^T,
// fp64 Gauss-Jordan in LDS. Barriers are uniform across batches.
// ---------------------------------------------------------------------------
__global__ __launch_bounds__(1024) void pinv_kernel(float* __restrict__ ws)
{
    __shared__ double As[8][81], G[8][81], Inv[8][81], Cm[8][81], fcol[8][9], smu[8][9];
    __shared__ float smom[8][64];
    const int b = threadIdx.x >> 7, t = threadIdx.x & 127;

    if (t < 54) {
        float v = 0.f;
#pragma unroll
        for (int k = 0; k < 8; ++k) v += ws[WS_MOM + (b * 8 + k) * 64 + t];
        smom[b][t] = v;
    }
    __syncthreads();
    if (t < 9) {
        const double m = (double)smom[b][t] / M_;
        smu[b][t] = m;
        ws[WS_MU + b * 9 + t] = (float)m;
    }
    __syncthreads();
    if (t < 81) {  // cov = Sum(yy^T) - M mu mu^T
        const int i = t / 9, j = t % 9;
        const int ii = i < j ? i : j, jj = i < j ? j : i;
        const int tri = ii * 9 - ii * (ii - 1) / 2 + (jj - ii);
        As[b][t] = (double)smom[b][9 + tri] - (double)M_ * smu[b][i] * smu[b][j];
    }
    __syncthreads();
    if (t < 81) {
        const int i = t / 9, j = t % 9;
        double sv = 0.0;
#pragma unroll
        for (int k = 0; k < 9; ++k) sv += As[b][k * 9 + i] * As[b][k * 9 + j];  // A^T A
        G[b][t] = sv;
        Inv[b][t] = (i == j) ? 1.0 : 0.0;
    }
    __syncthreads();

    for (int col = 0; col < 9; ++col) {
        const double p = G[b][col * 9 + col];  // all read before any write
        __syncthreads();
        if (t < 9) {
            G[b][col * 9 + t] /= p;
            Inv[b][col * 9 + t] /= p;
        }
        __syncthreads();
        if (t < 9 && t != col) fcol[b][t] = G[b][t * 9 + col];
        __syncthreads();
        if (t < 81) {
            const int r = t / 9, j = t % 9;
            if (r != col) {
                const double f = fcol[b][r];
                G[b][t]   -= f * G[b][col * 9 + j];
                Inv[b][t] -= f * Inv[b][col * 9 + j];
            }
        }
        __syncthreads();
    }

    if (t < 81) {  // C = inv(A^T A) A^T
        const int i = t / 9, j = t % 9;
        double sv = 0.0;
#pragma unroll
        for (int k = 0; k < 9; ++k) sv += Inv[b][i * 9 + k] * As[b][j * 9 + k];
        Cm[b][t] = sv;
    }
    __syncthreads();
    if (t < 81) {
        const int i = t / 9, j = t % 9;
        ws[WS_S + b * 81 + t] = (float)(Cm[b][i * 9 + j] + Cm[b][j * 9 + i]);  // S = C+C^T
    }
}

// ---------------------------------------------------------------------------
// Kernel 3: transposed-plane U (u_d[m], qa[m]) and QB; zero ACC/CNT.
// ---------------------------------------------------------------------------
__global__ __launch_bounds__(256) void prep_kernel(const float* __restrict__ outputs,
                                                   const float* __restrict__ targets,
                                                   float* __restrict__ ws)
{
    const int gid = blockIdx.x * 256 + threadIdx.x;
    if (gid == 0) {  // ws is re-poisoned before every call
        ws[WS_ACC] = 0.f;
        ((int*)ws)[WS_CNT] = 0;
    }

    if (gid < B_ * M_) {
        const int b = gid >> 11, m = gid & 2047;
        const float* S  = ws + WS_S + b * 81;
        const float* mu = ws + WS_MU + b * 9;
        const float* r  = targets + (size_t)gid * 9;
        float a[9];
#pragma unroll
        for (int d = 0; d < 9; ++d) a[d] = r[d] - mu[d];
        float* P = ws + WS_UT + b * 20480 + m;  // plane stride 2048
        float qa = 0.f;
#pragma unroll
        for (int d = 0; d < 9; ++d) {
            float u = 0.f;
#pragma unroll
            for (int e = 0; e < 9; ++e) u = fmaf(S[d * 9 + e], a[e], u);
            P[d * 2048] = u;
            qa = fmaf(u, a[d], qa);
        }
        P[9 * 2048] = 0.5f * qa;
    } else if (gid < B_ * (M_ + N_)) {
        const int g2 = gid - B_ * M_;
        const int b = g2 >> 11;
        const float* S = ws + WS_S + b * 81;
        const float* r = outputs + (size_t)g2 * 9;
        float bb[9];
#pragma unroll
        for (int d = 0; d < 9; ++d) bb[d] = r[d];
        float q = 0.f;
#pragma unroll
        for (int d = 0; d < 9; ++d) {
            float v = 0.f;
#pragma unroll
            for (int e = 0; e < 9; ++e) v = fmaf(S[d * 9 + e], bb[e], v);
            q = fmaf(v, bb[d], q);
        }
        ws[WS_QB + g2] = 0.5f * q;
    }
}

// ---------------------------------------------------------------------------
// Kernel 4: sum-of-top-64 per column. ONE column per wave (rounds 3-5 lesson:
// the allocator insists on 64 VGPRs for this kernel; 2 cols/wave needs 64
// regs of value array alone -> guaranteed spills. 1 col/wave: ua[32] + ~18
// temps fits 64 with headroom). M staged in 4 phases of 512 rows (20 KB LDS,
// transposed planes, float4/lane = 4 rows/read, all conflict-free).
// b-vector in SGPRs. Exact selection: monotone-uint binary search bits
// 31..12, ballot counting (v_cmp -> SGPR mask, s_bcnt on scalar pipe,
// wave-uniform thresholds). Constant indices everywhere; bit loop unroll 1.
// Per-block LDS reduction -> 1 atomic/block; last block writes final mean.
// ---------------------------------------------------------------------------
__global__ __launch_bounds__(256) void topk_kernel(const float* __restrict__ outputs,
                                                   float* __restrict__ ws,
                                                   float* __restrict__ out)
{
    __shared__ __align__(16) float sU[QROWS * 10];  // 20480 B: 10 planes x 512
    __shared__ float sRed[4];
    const int b = blockIdx.y;
    const int tid = threadIdx.x;
    const int wave = tid >> 6, lane = tid & 63;
    const int n = blockIdx.x * 4 + wave;  // this wave's column

    // Wave-uniform b-vector -> SGPRs (frees VGPRs, SGPR operand in v_fma).
    const float* brow = outputs + ((size_t)b * N_ + n) * 9;
    float sb[9];
#pragma unroll
    for (int d = 0; d < 9; ++d)
        sb[d] = __int_as_float(__builtin_amdgcn_readfirstlane(__float_as_int(brow[d])));

    unsigned ua[32];
#pragma unroll
    for (int ph = 0; ph < 4; ++ph) {
        __syncthreads();  // protect LDS from previous phase's readers
        const float4* srcB = (const float4*)ws + (WS_UT >> 2) + b * 5120 + ph * 128;
        float4* dst = (float4*)sU;
#pragma unroll
        for (int i = 0; i < 5; ++i) {
            const int t = tid + i * 256, p = t >> 7, r = t & 127;
            dst[t] = srcB[p * 512 + r];
        }
        __syncthreads();

#pragma unroll
        for (int j = 0; j < 2; ++j) {  // 256 rows per j, 4 rows/lane
            const int mi = j * 256 + lane * 4;
            const float4 q4 = *(const float4*)(sU + 9 * QROWS + mi);
            float a0 = q4.x, a1 = q4.y, a2 = q4.z, a3 = q4.w;
#pragma unroll
            for (int d = 0; d < 9; ++d) {
                const float4 u4 = *(const float4*)(sU + d * QROWS + mi);
                const float bd = sb[d];
                a0 = fmaf(-u4.x, bd, a0);
                a1 = fmaf(-u4.y, bd, a1);
                a2 = fmaf(-u4.z, bd, a2);
                a3 = fmaf(-u4.w, bd, a3);
            }
            const unsigned x0 = __float_as_uint(a0), x1 = __float_as_uint(a1);
            const unsigned x2 = __float_as_uint(a2), x3 = __float_as_uint(a3);
            ua[ph * 8 + j * 4 + 0] = (x0 & 0x80000000u) ? ~x0 : (x0 | 0x80000000u);
            ua[ph * 8 + j * 4 + 1] = (x1 & 0x80000000u) ? ~x1 : (x1 | 0x80000000u);
            ua[ph * 8 + j * 4 + 2] = (x2 & 0x80000000u) ? ~x2 : (x2 | 0x80000000u);
            ua[ph * 8 + j * 4 + 3] = (x3 & 0x80000000u) ? ~x3 : (x3 | 0x80000000u);
        }
    }

    // Binary search for tau (64th largest), bits 31..12 (rounds 2-5 verified
    // exact at this truncation). v_cmp -> SGPR mask; popcount+sum on the
    // scalar pipe; threshold ta is a wave-uniform SGPR.
    unsigned ca = 0u;
#pragma unroll 1
    for (int bit = 31; bit >= 12; --bit) {
        const unsigned ta = ca | (1u << bit);
        int cnt = 0;
#pragma unroll
        for (int j = 0; j < 32; ++j) cnt += __popcll(__ballot(ua[j] >= ta));
        if (cnt >= K_) ca = ta;
    }

    // Exact sum of values strictly above cand + tie adjustment at cand.
    // ga from ballots is already wave-uniform; only sa needs a butterfly.
    float sa = 0.f;
    int ga = 0;
#pragma unroll
    for (int j = 0; j < 32; ++j) {
        const unsigned va = ua[j];
        const float fa = __uint_as_float((va & 0x80000000u) ? (va ^ 0x80000000u) : ~va);
        const bool pa = va > ca;
        sa += pa ? fa : 0.f;
        ga += __popcll(__ballot(pa));
    }
#pragma unroll
    for (int o = 32; o; o >>= 1) sa += __shfl_xor(sa, o, 64);

    if (lane == 0) {
        const float tva = __uint_as_float((ca & 0x80000000u) ? (ca ^ 0x80000000u) : ~ca);
        const float qbn = ws[WS_QB + b * N_ + n];
        sRed[wave] = sa + (float)(K_ - ga) * tva + (float)K_ * qbn;
    }
    __syncthreads();
    if (tid == 0) {
        atomicAdd(ws + WS_ACC, sRed[0] + sRed[1] + sRed[2] + sRed[3]);
        __threadfence();
        const int done = atomicAdd((int*)ws + WS_CNT, 1);
        if (done == (N_ / 4) * B_ - 1) {  // last block: final mean, /2^20 exact
            __threadfence();
            const float acc = atomicAdd(ws + WS_ACC, 0.f);  // device-coherent read
            out[0] = acc * (1.0f / 1048576.0f);
        }
    }
}

// ---------------------------------------------------------------------------
extern "C" void kernel_launch(void* const* d_in, const int* in_sizes, int n_in,
                              void* d_out, int out_size, void* d_ws, size_t ws_size,
                              hipStream_t stream)
{
    (void)in_sizes; (void)n_in; (void)out_size; (void)ws_size;
    const float* outputs = (const float*)d_in[0];  // (B,N,9) fp32
    const float* targets = (const float*)d_in[1];  // (B,M,9) fp32
    float* ws  = (float*)d_ws;
    float* out = (float*)d_out;

    stats_kernel<<<dim3(8, B_), 256, 0, stream>>>(targets, ws);
    pinv_kernel<<<1, 1024, 0, stream>>>(ws);
    prep_kernel<<<(B_ * (M_ + N_)) / 256, 256, 0, stream>>>(outputs, targets, ws);
    topk_kernel<<<dim3(N_ / 4, B_), 256, 0, stream>>>(outputs, ws, out);
}

// Round 7
// 217.476 us; speedup vs baseline: 1.1979x; 1.0056x over previous
//
#include <hip/hip_runtime.h>
#include <stdint.h>

// Problem constants (fixed by reference setup_inputs)
constexpr int B_ = 8, N_ = 2048, M_ = 2048, K_ = 64;
constexpr int QROWS = 512;  // M rows staged in LDS per phase (4 phases)

// Workspace layout (float offsets). Total 188416 floats (~754 KB).
constexpr int WS_ACC = 0;       // [1]        global fp32 accumulator
constexpr int WS_CNT = 8;       // [1]        int done-counter for final reduce
constexpr int WS_MU  = 16;      // [B*9]      per-batch mean of targets
constexpr int WS_S   = 256;     // [B*81]     S = C + C^T (C = pinv(cov))
constexpr int WS_MOM = 1024;    // [B*8*64]   per-block raw-moment partials
constexpr int WS_QB  = 8192;    // [B*N]      qb = 0.5 b^T S b
constexpr int WS_UT  = 24576;   // [B][10][M] transposed planes: d=0..8 -> u_d[m], d=9 -> qa[m]

__device__ __forceinline__ unsigned mkey(float f) {  // monotone float->uint map
    const unsigned x = __float_as_uint(f);
    return (x & 0x80000000u) ? ~x : (x | 0x80000000u);
}
__device__ __forceinline__ float unkey(unsigned v) {
    return __uint_as_float((v & 0x80000000u) ? (v ^ 0x80000000u) : ~v);
}

// ---------------------------------------------------------------------------
// Kernel 1: raw moments per (row-block, batch): Sum(y)[9], Sum(yy^T)[45 tri].
// ---------------------------------------------------------------------------
__global__ __launch_bounds__(256) void stats_kernel(const float* __restrict__ targets,
                                                    float* __restrict__ ws)
{
    const int blk = blockIdx.x, b = blockIdx.y, tid = threadIdx.x;
    const float* row = targets + ((size_t)b * M_ + blk * 256 + tid) * 9;
    float y[9], s[9], cc[45];
#pragma unroll
    for (int d = 0; d < 9; ++d) { y[d] = row[d]; s[d] = y[d]; }
    int idx = 0;
#pragma unroll
    for (int i = 0; i < 9; ++i)
#pragma unroll
        for (int j = i; j < 9; ++j) { cc[idx] = y[i] * y[j]; ++idx; }
#pragma unroll
    for (int o = 32; o; o >>= 1) {
#pragma unroll
        for (int d = 0; d < 9; ++d) s[d] += __shfl_xor(s[d], o, 64);
#pragma unroll
        for (int i = 0; i < 45; ++i) cc[i] += __shfl_xor(cc[i], o, 64);
    }
    __shared__ float red[4][54];
    const int wave = tid >> 6, lane = tid & 63;
    if (lane == 0) {
#pragma unroll
        for (int d = 0; d < 9; ++d) red[wave][d] = s[d];
#pragma unroll
        for (int i = 0; i < 45; ++i) red[wave][9 + i] = cc[i];
    }
    __syncthreads();
    if (tid < 54)
        ws[WS_MOM + (b * 8 + blk) * 64 + tid] =
            red[0][tid] + red[1][tid] + red[2][tid] + red[3][tid];
}

// ---------------------------------------------------------------------------
// Kernel 2: ALL 8 batches' pinv in one 1024-thread block (128 threads/batch).
// ---------------------------------------------------------------------------
__global__ __launch_bounds__(1024) void pinv_kernel(float* __restrict__ ws)
{
    __shared__ double As[8][81], G[8][81], Inv[8][81], Cm[8][81], fcol[8][9], smu[8][9];
    __shared__ float smom[8][64];
    const int b = threadIdx.x >> 7, t = threadIdx.x & 127;

    if (t < 54) {
        float v = 0.f;
#pragma unroll
        for (int k = 0; k < 8; ++k) v += ws[WS_MOM + (b * 8 + k) * 64 + t];
        smom[b][t] = v;
    }
    __syncthreads();
    if (t < 9) {
        const double m = (double)smom[b][t] / M_;
        smu[b][t] = m;
        ws[WS_MU + b * 9 + t] = (float)m;
    }
    __syncthreads();
    if (t < 81) {  // cov = Sum(yy^T) - M mu mu^T
        const int i = t / 9, j = t % 9;
        const int ii = i < j ? i : j, jj = i < j ? j : i;
        const int tri = ii * 9 - ii * (ii - 1) / 2 + (jj - ii);
        As[b][t] = (double)smom[b][9 + tri] - (double)M_ * smu[b][i] * smu[b][j];
    }
    __syncthreads();
    if (t < 81) {
        const int i = t / 9, j = t % 9;
        double sv = 0.0;
#pragma unroll
        for (int k = 0; k < 9; ++k) sv += As[b][k * 9 + i] * As[b][k * 9 + j];  // A^T A
        G[b][t] = sv;
        Inv[b][t] = (i == j) ? 1.0 : 0.0;
    }
    __syncthreads();

    for (int col = 0; col < 9; ++col) {
        const double p = G[b][col * 9 + col];  // all read before any write
        __syncthreads();
        if (t < 9) {
            G[b][col * 9 + t] /= p;
            Inv[b][col * 9 + t] /= p;
        }
        __syncthreads();
        if (t < 9 && t != col) fcol[b][t] = G[b][t * 9 + col];
        __syncthreads();
        if (t < 81) {
            const int r = t / 9, j = t % 9;
            if (r != col) {
                const double f = fcol[b][r];
                G[b][t]   -= f * G[b][col * 9 + j];
                Inv[b][t] -= f * Inv[b][col * 9 + j];
            }
        }
        __syncthreads();
    }

    if (t < 81) {  // C = inv(A^T A) A^T
        const int i = t / 9, j = t % 9;
        double sv = 0.0;
#pragma unroll
        for (int k = 0; k < 9; ++k) sv += Inv[b][i * 9 + k] * As[b][j * 9 + k];
        Cm[b][t] = sv;
    }
    __syncthreads();
    if (t < 81) {
        const int i = t / 9, j = t % 9;
        ws[WS_S + b * 81 + t] = (float)(Cm[b][i * 9 + j] + Cm[b][j * 9 + i]);  // S = C+C^T
    }
}

// ---------------------------------------------------------------------------
// Kernel 3: transposed-plane U (u_d[m], qa[m]) and QB; zero ACC/CNT.
// ---------------------------------------------------------------------------
__global__ __launch_bounds__(256) void prep_kernel(const float* __restrict__ outputs,
                                                   const float* __restrict__ targets,
                                                   float* __restrict__ ws)
{
    const int gid = blockIdx.x * 256 + threadIdx.x;
    if (gid == 0) {  // ws is re-poisoned before every call
        ws[WS_ACC] = 0.f;
        ((int*)ws)[WS_CNT] = 0;
    }

    if (gid < B_ * M_) {
        const int b = gid >> 11, m = gid & 2047;
        const float* S  = ws + WS_S + b * 81;
        const float* mu = ws + WS_MU + b * 9;
        const float* r  = targets + (size_t)gid * 9;
        float a[9];
#pragma unroll
        for (int d = 0; d < 9; ++d) a[d] = r[d] - mu[d];
        float* P = ws + WS_UT + b * 20480 + m;  // plane stride 2048
        float qa = 0.f;
#pragma unroll
        for (int d = 0; d < 9; ++d) {
            float u = 0.f;
#pragma unroll
            for (int e = 0; e < 9; ++e) u = fmaf(S[d * 9 + e], a[e], u);
            P[d * 2048] = u;
            qa = fmaf(u, a[d], qa);
        }
        P[9 * 2048] = 0.5f * qa;
    } else if (gid < B_ * (M_ + N_)) {
        const int g2 = gid - B_ * M_;
        const int b = g2 >> 11;
        const float* S = ws + WS_S + b * 81;
        const float* r = outputs + (size_t)g2 * 9;
        float bb[9];
#pragma unroll
        for (int d = 0; d < 9; ++d) bb[d] = r[d];
        float q = 0.f;
#pragma unroll
        for (int d = 0; d < 9; ++d) {
            float v = 0.f;
#pragma unroll
            for (int e = 0; e < 9; ++e) v = fmaf(S[d * 9 + e], bb[e], v);
            q = fmaf(v, bb[d], q);
        }
        ws[WS_QB + g2] = 0.5f * q;
    }
}

// ---------------------------------------------------------------------------
// Kernel 4: sum-of-top-64 per column, 1 column/wave.
// ROUNDS 2-6 LESSON: a local ARRAY of 32 keys is a stack alloca the compiler
// never promotes (VGPR_Count 44-64 < array size every round; search loop was
// scratch-latency-bound at ~145 us regardless of structure). Fix: 32 NAMED
// scalars via macros -- cannot be an alloca, must be virtual registers.
// __launch_bounds__(256,2) -> 256-reg cap so ~60 live regs never spill.
// M staged in 4 phases of 512 rows (20 KB LDS, transposed planes,
// float4/lane, conflict-free). Exact selection: monotone-uint binary search
// bits 31..12 (verified exact, absmax 0.0), ballot counting.
// ---------------------------------------------------------------------------
__global__ __launch_bounds__(256, 2) void topk_kernel(const float* __restrict__ outputs,
                                                      float* __restrict__ ws,
                                                      float* __restrict__ out)
{
    __shared__ __align__(16) float sU[QROWS * 10];  // 20480 B: 10 planes x 512
    __shared__ float sRed[4];
    const int b = blockIdx.y;
    const int tid = threadIdx.x;
    const int wave = tid >> 6, lane = tid & 63;
    const int n = blockIdx.x * 4 + wave;  // this wave's column

    // Wave-uniform b-vector -> SGPRs.
    const float* brow = outputs + ((size_t)b * N_ + n) * 9;
    float sb[9];
#pragma unroll
    for (int d = 0; d < 9; ++d)
        sb[d] = __int_as_float(__builtin_amdgcn_readfirstlane(__float_as_int(brow[d])));

    unsigned u00, u01, u02, u03, u04, u05, u06, u07,
             u08, u09, u10, u11, u12, u13, u14, u15,
             u16, u17, u18, u19, u20, u21, u22, u23,
             u24, u25, u26, u27, u28, u29, u30, u31;

#define STAGE(ph)                                                              \
    __syncthreads();                                                           \
    {                                                                          \
        const float4* srcB = (const float4*)ws + (WS_UT >> 2) + b * 5120 + (ph) * 128; \
        float4* dst = (float4*)sU;                                             \
        _Pragma("unroll")                                                      \
        for (int i = 0; i < 5; ++i) {                                          \
            const int t = tid + i * 256, p = t >> 7, r = t & 127;              \
            dst[t] = srcB[p * 512 + r];                                        \
        }                                                                      \
    }                                                                          \
    __syncthreads();

#define COMP4(j, VA, VB, VC, VD)                                               \
    {                                                                          \
        const int mi = (j) * 256 + lane * 4;                                   \
        const float4 q4 = *(const float4*)(sU + 9 * QROWS + mi);               \
        float a0 = q4.x, a1 = q4.y, a2 = q4.z, a3 = q4.w;                      \
        _Pragma("unroll")                                                      \
        for (int d = 0; d < 9; ++d) {                                          \
            const float4 u4 = *(const float4*)(sU + d * QROWS + mi);           \
            const float bd = sb[d];                                            \
            a0 = fmaf(-u4.x, bd, a0);                                          \
            a1 = fmaf(-u4.y, bd, a1);                                          \
            a2 = fmaf(-u4.z, bd, a2);                                          \
            a3 = fmaf(-u4.w, bd, a3);                                          \
        }                                                                      \
        VA = mkey(a0); VB = mkey(a1); VC = mkey(a2); VD = mkey(a3);            \
    }

    STAGE(0) COMP4(0, u00, u01, u02, u03) COMP4(1, u04, u05, u06, u07)
    STAGE(1) COMP4(0, u08, u09, u10, u11) COMP4(1, u12, u13, u14, u15)
    STAGE(2) COMP4(0, u16, u17, u18, u19) COMP4(1, u20, u21, u22, u23)
    STAGE(3) COMP4(0, u24, u25, u26, u27) COMP4(1, u28, u29, u30, u31)
#undef STAGE
#undef COMP4

    // Binary search for tau (64th largest), bits 31..12 (verified exact).
    // v_cmp -> SGPR mask; popcount+sum on the scalar pipe; ta wave-uniform.
    unsigned ca = 0u;
#define CNT1(V) cnt += __popcll(__ballot((V) >= ta));
#pragma unroll 1
    for (int bit = 31; bit >= 12; --bit) {
        const unsigned ta = ca | (1u << bit);
        int cnt = 0;
        CNT1(u00) CNT1(u01) CNT1(u02) CNT1(u03) CNT1(u04) CNT1(u05) CNT1(u06) CNT1(u07)
        CNT1(u08) CNT1(u09) CNT1(u10) CNT1(u11) CNT1(u12) CNT1(u13) CNT1(u14) CNT1(u15)
        CNT1(u16) CNT1(u17) CNT1(u18) CNT1(u19) CNT1(u20) CNT1(u21) CNT1(u22) CNT1(u23)
        CNT1(u24) CNT1(u25) CNT1(u26) CNT1(u27) CNT1(u28) CNT1(u29) CNT1(u30) CNT1(u31)
        if (cnt >= K_) ca = ta;
    }
#undef CNT1

    // Exact sum of values strictly above cand + tie adjustment at cand.
    float sa = 0.f;
    int ga = 0;
#define EPI1(V)                                                                \
    {                                                                          \
        const bool p = (V) > ca;                                               \
        sa += p ? unkey(V) : 0.f;                                              \
        ga += __popcll(__ballot(p));                                           \
    }
    EPI1(u00) EPI1(u01) EPI1(u02) EPI1(u03) EPI1(u04) EPI1(u05) EPI1(u06) EPI1(u07)
    EPI1(u08) EPI1(u09) EPI1(u10) EPI1(u11) EPI1(u12) EPI1(u13) EPI1(u14) EPI1(u15)
    EPI1(u16) EPI1(u17) EPI1(u18) EPI1(u19) EPI1(u20) EPI1(u21) EPI1(u22) EPI1(u23)
    EPI1(u24) EPI1(u25) EPI1(u26) EPI1(u27) EPI1(u28) EPI1(u29) EPI1(u30) EPI1(u31)
#undef EPI1
#pragma unroll
    for (int o = 32; o; o >>= 1) sa += __shfl_xor(sa, o, 64);

    if (lane == 0) {
        const float tva = unkey(ca);
        const float qbn = ws[WS_QB + b * N_ + n];
        sRed[wave] = sa + (float)(K_ - ga) * tva + (float)K_ * qbn;
    }
    __syncthreads();
    if (tid == 0) {
        atomicAdd(ws + WS_ACC, sRed[0] + sRed[1] + sRed[2] + sRed[3]);
        __threadfence();
        const int done = atomicAdd((int*)ws + WS_CNT, 1);
        if (done == (N_ / 4) * B_ - 1) {  // last block: final mean, /2^20 exact
            __threadfence();
            const float acc = atomicAdd(ws + WS_ACC, 0.f);  // device-coherent read
            out[0] = acc * (1.0f / 1048576.0f);
        }
    }
}

// ---------------------------------------------------------------------------
extern "C" void kernel_launch(void* const* d_in, const int* in_sizes, int n_in,
                              void* d_out, int out_size, void* d_ws, size_t ws_size,
                              hipStream_t stream)
{
    (void)in_sizes; (void)n_in; (void)out_size; (void)ws_size;
    const float* outputs = (const float*)d_in[0];  // (B,N,9) fp32
    const float* targets = (const float*)d_in[1];  // (B,M,9) fp32
    float* ws  = (float*)d_ws;
    float* out = (float*)d_out;

    stats_kernel<<<dim3(8, B_), 256, 0, stream>>>(targets, ws);
    pinv_kernel<<<1, 1024, 0, stream>>>(ws);
    prep_kernel<<<(B_ * (M_ + N_)) / 256, 256, 0, stream>>>(outputs, targets, ws);
    topk_kernel<<<dim3(N_ / 4, B_), 256, 0, stream>>>(outputs, ws, out);
}